// Round 1
// baseline (320.982 us; speedup 1.0000x reference)
//
#include <hip/hip_runtime.h>

#define DIM 32
#define HID 64
#define W1ROW 36   // 32 g-weights + pot-weight + b1 + 2 pad (144 B, float4 aligned)

__global__ __launch_bounds__(256) void behavior_kernel(
    const float* __restrict__ g_in,   // [N, 32]
    const float* __restrict__ pot,    // [N]
    const float* __restrict__ W1,     // [33, 64] row-major
    const float* __restrict__ b1,     // [64]
    const float* __restrict__ W2,     // [64, 32] row-major
    const float* __restrict__ b2,     // [32]
    float* __restrict__ out)          // [N, 32]
{
    __shared__ __align__(16) float sW1[HID * W1ROW]; // sW1[f*36+c]: c<33 -> W1[c][f], c==33 -> b1[f]
    __shared__ __align__(16) float sW2[HID * DIM];   // row f contiguous
    __shared__ __align__(16) float sB2[DIM];

    const int tid = threadIdx.x;

    // ---- stage weights into LDS (transpose W1, fold b1 in) ----
    for (int i = tid; i < 33 * HID; i += 256) {
        int c = i >> 6;        // i / 64
        int f = i & 63;        // i % 64
        sW1[f * W1ROW + c] = W1[i];
    }
    for (int i = tid; i < HID; i += 256) {
        sW1[i * W1ROW + 33] = b1[i];
        sW1[i * W1ROW + 34] = 0.0f;
        sW1[i * W1ROW + 35] = 0.0f;
    }
    for (int i = tid; i < HID * DIM; i += 256) sW2[i] = W2[i];
    if (tid < DIM) sB2[tid] = b2[tid];
    __syncthreads();

    const int cell = blockIdx.x * 256 + tid;
    const float* gp = g_in + (size_t)cell * DIM;

    // ---- load g, compute self-similarity pattern ----
    float g[DIM];
    #pragma unroll
    for (int j = 0; j < DIM / 4; ++j) {
        float4 v = ((const float4*)gp)[j];
        g[4 * j + 0] = v.x; g[4 * j + 1] = v.y;
        g[4 * j + 2] = v.z; g[4 * j + 3] = v.w;
    }
    const float p = pot[cell];

    float t = 0.0f, s = 0.0f;
    float x[DIM];
    #pragma unroll
    for (int c = 0; c < DIM; ++c) {
        float gc = g[c];
        float g2 = gc * gc;
        float g3 = g2 * gc;
        t += g2;
        s = fmaf(g3, g3, s);
        x[c] = g3;                      // hold cube temporarily
    }
    // self_pattern scale: 0.1 * ||g|| / (||g^3|| + eps)
    const float scale = 0.1f * sqrtf(t) / (sqrtf(s) + 1e-8f);

    float acc[DIM];
    #pragma unroll
    for (int c = 0; c < DIM; ++c) {
        x[c] = fmaf(scale, x[c], g[c]);          // x = g + 0.1*pattern
        acc[c] = fmaf(0.3f, g[c], sB2[c]);       // out starts at b2 + 0.3*g
    }

    // ---- h = relu(x @ W1 + b1); out += h @ W2  (fused over f) ----
    #pragma unroll 2
    for (int f = 0; f < HID; ++f) {
        const float4* w1row = (const float4*)&sW1[f * W1ROW];
        float hv = 0.0f;
        #pragma unroll
        for (int q = 0; q < 8; ++q) {
            float4 wv = w1row[q];
            hv = fmaf(x[4 * q + 0], wv.x, hv);
            hv = fmaf(x[4 * q + 1], wv.y, hv);
            hv = fmaf(x[4 * q + 2], wv.z, hv);
            hv = fmaf(x[4 * q + 3], wv.w, hv);
        }
        float4 wt = w1row[8];              // {W1[32][f], b1[f], 0, 0}
        hv = fmaf(p, wt.x, hv) + wt.y;
        hv = fmaxf(hv, 0.0f);

        const float4* w2row = (const float4*)&sW2[f * DIM];
        #pragma unroll
        for (int q = 0; q < 8; ++q) {
            float4 wv = w2row[q];
            acc[4 * q + 0] = fmaf(hv, wv.x, acc[4 * q + 0]);
            acc[4 * q + 1] = fmaf(hv, wv.y, acc[4 * q + 1]);
            acc[4 * q + 2] = fmaf(hv, wv.z, acc[4 * q + 2]);
            acc[4 * q + 3] = fmaf(hv, wv.w, acc[4 * q + 3]);
        }
    }

    // ---- store ----
    float* op = out + (size_t)cell * DIM;
    #pragma unroll
    for (int j = 0; j < DIM / 4; ++j) {
        ((float4*)op)[j] = make_float4(acc[4 * j + 0], acc[4 * j + 1],
                                       acc[4 * j + 2], acc[4 * j + 3]);
    }
}

extern "C" void kernel_launch(void* const* d_in, const int* in_sizes, int n_in,
                              void* d_out, int out_size, void* d_ws, size_t ws_size,
                              hipStream_t stream) {
    const float* g_in = (const float*)d_in[0];   // [1024*1024, 32]
    const float* pot  = (const float*)d_in[1];   // [1024*1024]
    const float* W1   = (const float*)d_in[2];   // [33, 64]
    const float* b1   = (const float*)d_in[3];   // [64]
    const float* W2   = (const float*)d_in[4];   // [64, 32]
    const float* b2   = (const float*)d_in[5];   // [32]
    float* out = (float*)d_out;

    const int n_cells = in_sizes[1];             // 1048576
    const int blocks = (n_cells + 255) / 256;

    behavior_kernel<<<blocks, 256, 0, stream>>>(g_in, pot, W1, b1, W2, b2, out);
}

// Round 2
// 264.315 us; speedup vs baseline: 1.2144x; 1.2144x over previous
//
#include <hip/hip_runtime.h>

#define DIM   32
#define HID   64
#define TILES 8              // 16-cell tiles per wave
#define HPAD  72             // h LDS row stride in bf16 (144 B, 16B-aligned)

typedef __attribute__((ext_vector_type(8))) short bf16x8;   // 8 bf16 = 4 VGPRs
typedef __attribute__((ext_vector_type(4))) float f32x4;

__device__ __forceinline__ short f2bf(float f) {
    union { float f; unsigned u; } v; v.f = f;
    unsigned r = (v.u + 0x7FFFu + ((v.u >> 16) & 1u)) >> 16;  // RNE
    return (short)r;
}

__global__ __launch_bounds__(256) void behavior_mfma(
    const float* __restrict__ g_in,   // [N, 32]
    const float* __restrict__ pot,    // [N]
    const float* __restrict__ W1,     // [33, 64]
    const float* __restrict__ b1,     // [64]
    const float* __restrict__ W2,     // [64, 32]
    const float* __restrict__ b2,     // [32]
    float* __restrict__ out,          // [N, 32]
    int n_cells)
{
    // per-wave private h tile: [16 cells][HPAD bf16]
    __shared__ __align__(16) short sH[4 * 16 * HPAD];

    const int tid  = threadIdx.x;
    const int lane = tid & 63;
    const int quad = lane >> 4;        // 0..3
    const int mrow = lane & 15;        // 0..15
    const int wave = tid >> 6;         // 0..3
    short* hbase = &sH[wave * 16 * HPAD];

    // ---- B-fragments: W1 (K=32 chunk), 4 n-chunks of 16 ----
    // B[k][n]: lane holds k = quad*8+j, n = nb*16 + mrow
    bf16x8 w1f[4];
    #pragma unroll
    for (int nb = 0; nb < 4; ++nb) {
        #pragma unroll
        for (int j = 0; j < 8; ++j)
            w1f[nb][j] = f2bf(W1[(quad * 8 + j) * HID + nb * 16 + mrow]);
    }
    // epilogue consts for GEMM1: potential row of W1, and b1
    float w1p[4], b1v[4];
    #pragma unroll
    for (int nb = 0; nb < 4; ++nb) {
        w1p[nb] = W1[32 * HID + nb * 16 + mrow];
        b1v[nb] = b1[nb * 16 + mrow];
    }
    // ---- B-fragments: W2, 2 k-chunks x 2 n-chunks ----
    bf16x8 w2f[2][2];
    #pragma unroll
    for (int kc = 0; kc < 2; ++kc)
        #pragma unroll
        for (int nc = 0; nc < 2; ++nc)
            #pragma unroll
            for (int j = 0; j < 8; ++j)
                w2f[kc][nc][j] = f2bf(W2[(kc * 32 + quad * 8 + j) * DIM + nc * 16 + mrow]);
    float b2v[2];
    #pragma unroll
    for (int nc = 0; nc < 2; ++nc) b2v[nc] = b2[nc * 16 + mrow];

    const f32x4 zacc = {0.f, 0.f, 0.f, 0.f};
    const int wave_id = blockIdx.x * 4 + wave;

    for (int t = 0; t < TILES; ++t) {
        const int cellbase = (wave_id * TILES + t) * 16;
        if (cellbase >= n_cells) break;

        // ---- load g: lane handles cell mrow, channels quad*8..quad*8+7 ----
        const float* gp = g_in + (size_t)(cellbase + mrow) * DIM + quad * 8;
        float gv[8];
        {
            float4 a = ((const float4*)gp)[0];
            float4 b = ((const float4*)gp)[1];
            gv[0]=a.x; gv[1]=a.y; gv[2]=a.z; gv[3]=a.w;
            gv[4]=b.x; gv[5]=b.y; gv[6]=b.z; gv[7]=b.w;
        }
        // potentials for this lane's C-layout rows (quad*4+reg)
        float pv[4];
        #pragma unroll
        for (int r = 0; r < 4; ++r) pv[r] = pot[cellbase + quad * 4 + r];

        // ---- self-similarity pattern: x = g + 0.1*||g||/(||g^3||+eps)*g^3 ----
        float cube[8];
        float tp = 0.f, sp = 0.f;
        #pragma unroll
        for (int j = 0; j < 8; ++j) {
            float gc = gv[j];
            float g2 = gc * gc;
            float g3 = g2 * gc;
            tp += g2;
            sp = fmaf(g3, g3, sp);
            cube[j] = g3;
        }
        // reduce over the 4 lanes holding the same cell (l, l^16, l^32, l^48)
        tp += __shfl_xor(tp, 16, 64); tp += __shfl_xor(tp, 32, 64);
        sp += __shfl_xor(sp, 16, 64); sp += __shfl_xor(sp, 32, 64);
        const float scale = 0.1f * sqrtf(tp) / (sqrtf(sp) + 1e-8f);

        // A-fragment of x (layout: m=mrow, k=quad*8+j) — already in place!
        bf16x8 xf;
        #pragma unroll
        for (int j = 0; j < 8; ++j) xf[j] = f2bf(fmaf(scale, cube[j], gv[j]));

        // ---- GEMM1: h = relu(x@W1[:32] + p*W1[32] + b1) ----
        #pragma unroll
        for (int nb = 0; nb < 4; ++nb) {
            f32x4 acc = __builtin_amdgcn_mfma_f32_16x16x32_bf16(xf, w1f[nb], zacc, 0, 0, 0);
            #pragma unroll
            for (int r = 0; r < 4; ++r) {
                // C layout: row = quad*4+r, col = nb*16+mrow
                float hv = acc[r] + fmaf(pv[r], w1p[nb], b1v[nb]);
                hv = fmaxf(hv, 0.f);
                hbase[(quad * 4 + r) * HPAD + nb * 16 + mrow] = f2bf(hv);
            }
        }

        // ---- h: C-layout -> A-layout via per-wave LDS (no barrier needed) ----
        bf16x8 hf[2];
        #pragma unroll
        for (int kc = 0; kc < 2; ++kc)
            hf[kc] = *(const bf16x8*)&hbase[mrow * HPAD + kc * 32 + quad * 8];

        // ---- GEMM2 + epilogue: out = h@W2 + b2 + 0.3*g ----
        #pragma unroll
        for (int nc = 0; nc < 2; ++nc) {
            f32x4 acc = __builtin_amdgcn_mfma_f32_16x16x32_bf16(hf[0], w2f[0][nc], zacc, 0, 0, 0);
            acc = __builtin_amdgcn_mfma_f32_16x16x32_bf16(hf[1], w2f[1][nc], acc, 0, 0, 0);
            #pragma unroll
            for (int r = 0; r < 4; ++r) {
                const int row = quad * 4 + r;
                const size_t idx = (size_t)(cellbase + row) * DIM + nc * 16 + mrow;
                out[idx] = acc[r] + b2v[nc] + 0.3f * g_in[idx];  // g reload: L1-hot
            }
        }
    }
}

extern "C" void kernel_launch(void* const* d_in, const int* in_sizes, int n_in,
                              void* d_out, int out_size, void* d_ws, size_t ws_size,
                              hipStream_t stream) {
    const float* g_in = (const float*)d_in[0];
    const float* pot  = (const float*)d_in[1];
    const float* W1   = (const float*)d_in[2];
    const float* b1   = (const float*)d_in[3];
    const float* W2   = (const float*)d_in[4];
    const float* b2   = (const float*)d_in[5];
    float* out = (float*)d_out;

    const int n_cells = in_sizes[1];                     // 1048576
    const int cells_per_block = 4 * TILES * 16;          // 512
    const int blocks = (n_cells + cells_per_block - 1) / cells_per_block;

    behavior_mfma<<<blocks, 256, 0, stream>>>(g_in, pot, W1, b1, W2, b2, out, n_cells);
}

// Round 3
// 255.109 us; speedup vs baseline: 1.2582x; 1.0361x over previous
//
#include <hip/hip_runtime.h>

#define DIM   32
#define HID   64
#define TILES 8              // 16-cell tiles per wave
#define HPAD  72             // h LDS row stride in bf16 (144 B, 16B-aligned)

typedef __attribute__((ext_vector_type(8))) short bf16x8;   // 8 bf16 = 4 VGPRs
typedef __attribute__((ext_vector_type(4))) float f32x4;

__device__ __forceinline__ short f2bf(float f) {
    union { float f; unsigned u; } v; v.f = f;
    unsigned r = (v.u + 0x7FFFu + ((v.u >> 16) & 1u)) >> 16;  // RNE
    return (short)r;
}

__global__ __launch_bounds__(256) void behavior_mfma(
    const float* __restrict__ g_in,   // [N, 32]
    const float* __restrict__ pot,    // [N]
    const float* __restrict__ W1,     // [33, 64]
    const float* __restrict__ b1,     // [64]
    const float* __restrict__ W2,     // [64, 32]
    const float* __restrict__ b2,     // [32]
    float* __restrict__ out)          // [N, 32]
{
    // per-wave private h tile: [16 cells][HPAD bf16]
    __shared__ __align__(16) short sH[4 * 16 * HPAD];

    const int tid  = threadIdx.x;
    const int lane = tid & 63;
    const int quad = lane >> 4;        // 0..3
    const int mrow = lane & 15;        // 0..15
    const int wave = tid >> 6;         // 0..3
    short* hbase = &sH[wave * 16 * HPAD];

    // ---- B-fragments: W1 (K=32), 4 n-chunks. B[k= quad*8+j][n= nb*16+mrow] ----
    bf16x8 w1f[4];
    float  w1p[4], b1v[4];
    #pragma unroll
    for (int nb = 0; nb < 4; ++nb) {
        #pragma unroll
        for (int j = 0; j < 8; ++j)
            w1f[nb][j] = f2bf(W1[(quad * 8 + j) * HID + nb * 16 + mrow]);
        w1p[nb] = W1[32 * HID + nb * 16 + mrow];
        b1v[nb] = b1[nb * 16 + mrow];
    }
    // ---- B-fragments: W2 (2 k-chunks x 2 n-chunks) ----
    bf16x8 w2f[2][2];
    #pragma unroll
    for (int kc = 0; kc < 2; ++kc)
        #pragma unroll
        for (int nc = 0; nc < 2; ++nc)
            #pragma unroll
            for (int j = 0; j < 8; ++j)
                w2f[kc][nc][j] = f2bf(W2[(kc * 32 + quad * 8 + j) * DIM + nc * 16 + mrow]);
    float b2v[2];
    #pragma unroll
    for (int nc = 0; nc < 2; ++nc) b2v[nc] = b2[nc * 16 + mrow];

    // ---- identity B-fragment for the 0.3*g pass-through (K-chunk 3 of GEMM2) ----
    bf16x8 idf[2];
    #pragma unroll
    for (int nc = 0; nc < 2; ++nc)
        #pragma unroll
        for (int j = 0; j < 8; ++j)
            idf[nc][j] = (quad * 8 + j == nc * 16 + mrow) ? (short)0x3F80 : (short)0;

    const long wave_id = (long)blockIdx.x * 4 + wave;
    const long cell0   = wave_id * (TILES * 16);

    // ---- software pipeline: prefetch tile t+1 while computing tile t ----
    float4 cga, cgb, cpv;
    {
        const float* gp = g_in + (cell0 + mrow) * DIM + quad * 8;
        cga = ((const float4*)gp)[0];
        cgb = ((const float4*)gp)[1];
        cpv = *(const float4*)(pot + cell0 + quad * 4);
    }

    #pragma unroll
    for (int t = 0; t < TILES; ++t) {
        float4 nga, ngb, npv;
        if (t + 1 < TILES) {
            const long cb = cell0 + (long)(t + 1) * 16;
            const float* gp = g_in + (cb + mrow) * DIM + quad * 8;
            nga = ((const float4*)gp)[0];
            ngb = ((const float4*)gp)[1];
            npv = *(const float4*)(pot + cb + quad * 4);
        }

        const long cb = cell0 + (long)t * 16;
        float gv[8] = {cga.x, cga.y, cga.z, cga.w, cgb.x, cgb.y, cgb.z, cgb.w};
        float pvr[4] = {cpv.x, cpv.y, cpv.z, cpv.w};

        // ---- self-similarity: scale = 0.1*||g|| / (||g^3||+eps) ----
        float cube[8];
        float tp = 0.f, sp = 0.f;
        #pragma unroll
        for (int j = 0; j < 8; ++j) {
            float gc = gv[j];
            float g2 = gc * gc;
            float g3 = g2 * gc;
            tp += g2;
            sp = fmaf(g3, g3, sp);
            cube[j] = g3;
        }
        tp += __shfl_xor(tp, 16, 64); tp += __shfl_xor(tp, 32, 64);
        sp += __shfl_xor(sp, 16, 64); sp += __shfl_xor(sp, 32, 64);
        const float scale = 0.1f * sqrtf(tp) / (sqrtf(sp) + 1e-8f);

        // A-fragments: x = g + scale*g^3, and 0.3*g (both at m=mrow, k=quad*8+j)
        bf16x8 xf, gf;
        #pragma unroll
        for (int j = 0; j < 8; ++j) {
            xf[j] = f2bf(fmaf(scale, cube[j], gv[j]));
            gf[j] = f2bf(0.3f * gv[j]);
        }

        // ---- GEMM1: h = relu(x@W1[:32] + (p*W1[32] + b1 folded into C)) ----
        #pragma unroll
        for (int nb = 0; nb < 4; ++nb) {
            f32x4 c1;
            #pragma unroll
            for (int r = 0; r < 4; ++r) c1[r] = fmaf(pvr[r], w1p[nb], b1v[nb]);
            c1 = __builtin_amdgcn_mfma_f32_16x16x32_bf16(xf, w1f[nb], c1, 0, 0, 0);
            #pragma unroll
            for (int r = 0; r < 4; ++r)
                hbase[(quad * 4 + r) * HPAD + nb * 16 + mrow] = f2bf(fmaxf(c1[r], 0.f));
        }

        // ---- h: C-layout -> A-layout via per-wave LDS (no barrier needed) ----
        bf16x8 hf0 = *(const bf16x8*)&hbase[mrow * HPAD +  0 + quad * 8];
        bf16x8 hf1 = *(const bf16x8*)&hbase[mrow * HPAD + 32 + quad * 8];

        // ---- GEMM2: out = [h ; 0.3g] @ [W2 ; I] + b2 (b2 folded into C) ----
        #pragma unroll
        for (int nc = 0; nc < 2; ++nc) {
            f32x4 c2 = {b2v[nc], b2v[nc], b2v[nc], b2v[nc]};
            c2 = __builtin_amdgcn_mfma_f32_16x16x32_bf16(gf, idf[nc],    c2, 0, 0, 0); // LDS-independent first
            c2 = __builtin_amdgcn_mfma_f32_16x16x32_bf16(hf0, w2f[0][nc], c2, 0, 0, 0);
            c2 = __builtin_amdgcn_mfma_f32_16x16x32_bf16(hf1, w2f[1][nc], c2, 0, 0, 0);
            #pragma unroll
            for (int r = 0; r < 4; ++r)
                out[(cb + quad * 4 + r) * DIM + nc * 16 + mrow] = c2[r];
        }

        cga = nga; cgb = ngb; cpv = npv;
    }
}

extern "C" void kernel_launch(void* const* d_in, const int* in_sizes, int n_in,
                              void* d_out, int out_size, void* d_ws, size_t ws_size,
                              hipStream_t stream) {
    const float* g_in = (const float*)d_in[0];
    const float* pot  = (const float*)d_in[1];
    const float* W1   = (const float*)d_in[2];
    const float* b1   = (const float*)d_in[3];
    const float* W2   = (const float*)d_in[4];
    const float* b2   = (const float*)d_in[5];
    float* out = (float*)d_out;

    const int n_cells = in_sizes[1];                     // 1048576
    const int cells_per_block = 4 * TILES * 16;          // 512
    const int blocks = (n_cells + cells_per_block - 1) / cells_per_block;

    behavior_mfma<<<blocks, 256, 0, stream>>>(g_in, pot, W1, b1, W2, b2, out);
}

// Round 4
// 252.106 us; speedup vs baseline: 1.2732x; 1.0119x over previous
//
#include <hip/hip_runtime.h>

#define DIM   32
#define HID   64
#define TILES 8              // 16-cell tiles per wave
#define HPAD  72             // h LDS row stride in bf16 (144 B, 16B-aligned)
#define HBUF  (16 * HPAD)    // one h buffer (shorts) per wave

typedef __attribute__((ext_vector_type(8))) short bf16x8;   // 8 bf16 = 4 VGPRs
typedef __attribute__((ext_vector_type(4))) float f32x4;

__device__ __forceinline__ short f2bf(float f) {
    union { float f; unsigned u; } v; v.f = f;
    unsigned r = (v.u + 0x7FFFu + ((v.u >> 16) & 1u)) >> 16;  // RNE
    return (short)r;
}

__global__ __launch_bounds__(256) void behavior_mfma(
    const float* __restrict__ g_in,   // [N, 32]
    const float* __restrict__ pot,    // [N]
    const float* __restrict__ W1,     // [33, 64]
    const float* __restrict__ b1,     // [64]
    const float* __restrict__ W2,     // [64, 32]
    const float* __restrict__ b2,     // [32]
    float* __restrict__ out)          // [N, 32]
{
    // per-wave DOUBLE-buffered h tile: 2 x [16 cells][HPAD bf16]
    __shared__ __align__(16) short sH[4 * 2 * HBUF];

    const int tid  = threadIdx.x;
    const int lane = tid & 63;
    const int quad = lane >> 4;        // 0..3
    const int mrow = lane & 15;        // 0..15
    const int wave = tid >> 6;         // 0..3
    short* hb = &sH[wave * 2 * HBUF];

    // ---- B-fragments: W1 (K=32), 4 n-chunks. B[k= quad*8+j][n= nb*16+mrow] ----
    bf16x8 w1f[4];
    float  w1p[4], b1v[4];
    #pragma unroll
    for (int nb = 0; nb < 4; ++nb) {
        #pragma unroll
        for (int j = 0; j < 8; ++j)
            w1f[nb][j] = f2bf(W1[(quad * 8 + j) * HID + nb * 16 + mrow]);
        w1p[nb] = W1[32 * HID + nb * 16 + mrow];
        b1v[nb] = b1[nb * 16 + mrow];
    }
    // ---- B-fragments: W2 (2 k-chunks x 2 n-chunks) ----
    bf16x8 w2f[2][2];
    #pragma unroll
    for (int kc = 0; kc < 2; ++kc)
        #pragma unroll
        for (int nc = 0; nc < 2; ++nc)
            #pragma unroll
            for (int j = 0; j < 8; ++j)
                w2f[kc][nc][j] = f2bf(W2[(kc * 32 + quad * 8 + j) * DIM + nc * 16 + mrow]);
    float b2v[2];
    #pragma unroll
    for (int nc = 0; nc < 2; ++nc) b2v[nc] = b2[nc * 16 + mrow];

    // ---- identity B-fragment for the 0.3*g pass-through (K-chunk 3 of GEMM2) ----
    bf16x8 idf[2];
    #pragma unroll
    for (int nc = 0; nc < 2; ++nc)
        #pragma unroll
        for (int j = 0; j < 8; ++j)
            idf[nc][j] = (quad * 8 + j == nc * 16 + mrow) ? (short)0x3F80 : (short)0;

    const long cell0 = ((long)blockIdx.x * 4 + wave) * (TILES * 16);

    // ---------- pipeline helpers ----------
    auto loadTile = [&](long cb, float4& a, float4& b, float4& p) {
        const float* gp = g_in + (cb + mrow) * DIM + quad * 8;
        a = ((const float4*)gp)[0];
        b = ((const float4*)gp)[1];
        p = *(const float4*)(pot + cb + quad * 4);
    };

    // norm + GEMM1 + h->LDS(buf) + produce gf (0.3g A-frag)
    auto stageA = [&](const float4& a, const float4& b, const float4& p,
                      short* buf, bf16x8& gf_out) {
        float gv[8] = {a.x, a.y, a.z, a.w, b.x, b.y, b.z, b.w};
        float cube[8];
        float tp = 0.f, sp = 0.f;
        #pragma unroll
        for (int j = 0; j < 8; ++j) {
            float gc = gv[j];
            float g2 = gc * gc;
            float g3 = g2 * gc;
            tp += g2;
            sp = fmaf(g3, g3, sp);
            cube[j] = g3;
        }
        tp += __shfl_xor(tp, 16, 64); tp += __shfl_xor(tp, 32, 64);
        sp += __shfl_xor(sp, 16, 64); sp += __shfl_xor(sp, 32, 64);
        const float scale = 0.1f * sqrtf(tp) / (sqrtf(sp) + 1e-8f);

        bf16x8 xf;
        #pragma unroll
        for (int j = 0; j < 8; ++j) {
            xf[j]     = f2bf(fmaf(scale, cube[j], gv[j]));
            gf_out[j] = f2bf(0.3f * gv[j]);
        }
        const float pvr[4] = {p.x, p.y, p.z, p.w};
        #pragma unroll
        for (int nb = 0; nb < 4; ++nb) {
            f32x4 c1;
            #pragma unroll
            for (int r = 0; r < 4; ++r) c1[r] = fmaf(pvr[r], w1p[nb], b1v[nb]);
            c1 = __builtin_amdgcn_mfma_f32_16x16x32_bf16(xf, w1f[nb], c1, 0, 0, 0);
            #pragma unroll
            for (int r = 0; r < 4; ++r)
                buf[(quad * 4 + r) * HPAD + nb * 16 + mrow] = f2bf(fmaxf(c1[r], 0.f));
        }
    };

    auto gemm2 = [&](const bf16x8& hf0, const bf16x8& hf1, const bf16x8& gfv, long cb) {
        #pragma unroll
        for (int nc = 0; nc < 2; ++nc) {
            f32x4 c2 = {b2v[nc], b2v[nc], b2v[nc], b2v[nc]};
            c2 = __builtin_amdgcn_mfma_f32_16x16x32_bf16(gfv, idf[nc],    c2, 0, 0, 0);
            c2 = __builtin_amdgcn_mfma_f32_16x16x32_bf16(hf0, w2f[0][nc], c2, 0, 0, 0);
            c2 = __builtin_amdgcn_mfma_f32_16x16x32_bf16(hf1, w2f[1][nc], c2, 0, 0, 0);
            #pragma unroll
            for (int r = 0; r < 4; ++r)
                out[(cb + quad * 4 + r) * DIM + nc * 16 + mrow] = c2[r];
        }
    };

    // ---------- 2-stage software pipeline over tiles ----------
    float4 cga, cgb, cpv, nga, ngb, npv;
    bf16x8 gfP, gfC;

    loadTile(cell0, cga, cgb, cpv);
    loadTile(cell0 + 16, nga, ngb, npv);
    stageA(cga, cgb, cpv, hb, gfP);                     // tile 0 -> buf 0

    #pragma unroll 2
    for (int t = 1; t < TILES; ++t) {
        // 1) issue ds_reads for h(t-1) early — latency hidden by stageA(t)
        short* rbuf = hb + ((t - 1) & 1) * HBUF;
        bf16x8 hf0 = *(const bf16x8*)&rbuf[mrow * HPAD +  0 + quad * 8];
        bf16x8 hf1 = *(const bf16x8*)&rbuf[mrow * HPAD + 32 + quad * 8];

        // 2) rotate prefetch regs, issue global loads for tile t+1
        cga = nga; cgb = ngb; cpv = npv;
        if (t + 1 < TILES)
            loadTile(cell0 + (long)(t + 1) * 16, nga, ngb, npv);

        // 3) stage A for tile t (norm + GEMM1 + ds_write into other buffer)
        stageA(cga, cgb, cpv, hb + (t & 1) * HBUF, gfC);

        // 4) stage B for tile t-1 (GEMM2 + store)
        gemm2(hf0, hf1, gfP, cell0 + (long)(t - 1) * 16);
        gfP = gfC;
    }

    // epilogue: stage B for the last tile
    {
        short* rbuf = hb + ((TILES - 1) & 1) * HBUF;
        bf16x8 hf0 = *(const bf16x8*)&rbuf[mrow * HPAD +  0 + quad * 8];
        bf16x8 hf1 = *(const bf16x8*)&rbuf[mrow * HPAD + 32 + quad * 8];
        gemm2(hf0, hf1, gfP, cell0 + (long)(TILES - 1) * 16);
    }
}

extern "C" void kernel_launch(void* const* d_in, const int* in_sizes, int n_in,
                              void* d_out, int out_size, void* d_ws, size_t ws_size,
                              hipStream_t stream) {
    const float* g_in = (const float*)d_in[0];
    const float* pot  = (const float*)d_in[1];
    const float* W1   = (const float*)d_in[2];
    const float* b1   = (const float*)d_in[3];
    const float* W2   = (const float*)d_in[4];
    const float* b2   = (const float*)d_in[5];
    float* out = (float*)d_out;

    const int n_cells = in_sizes[1];                     // 1048576
    const int cells_per_block = 4 * TILES * 16;          // 512
    const int blocks = (n_cells + cells_per_block - 1) / cells_per_block;

    behavior_mfma<<<blocks, 256, 0, stream>>>(g_in, pot, W1, b1, W2, b2, out);
}